// Round 5
// baseline (423.266 us; speedup 1.0000x reference)
//
#include <hip/hip_runtime.h>
#include <cfloat>
#include <math.h>

#define NUM_EMB 8192
#define DIM 256
#define NROWS 32768

typedef short s8v __attribute__((ext_vector_type(8)));   // 8 bf16 in 4 VGPRs
typedef float f32x4 __attribute__((ext_vector_type(4)));

#define GL2LDS(g, l) __builtin_amdgcn_global_load_lds( \
    (const __attribute__((address_space(1))) void*)(g), \
    (__attribute__((address_space(3))) void*)(l), 16, 0, 0)

// fp32 -> bf16 (round-to-nearest-even), header-version-independent
__device__ __forceinline__ unsigned short f2bf(float f) {
    unsigned int u = __float_as_uint(f);
    u += 0x7fffu + ((u >> 16) & 1u);
    return (unsigned short)(u >> 16);
}

// ---------------- fused: x->bf16  +  codebook norms/bf16 ----------------
// blocks [0,8192): convert x ; blocks [8192,10240): codebook rows (4/block)
__global__ __launch_bounds__(256) void vq_prep(const float* __restrict__ x,
                                               unsigned short* __restrict__ xb,
                                               const float* __restrict__ cb,
                                               unsigned short* __restrict__ cbb,
                                               float* __restrict__ cbn) {
    int b = blockIdx.x;
    if (b < 8192) {
        int i = b * 256 + threadIdx.x;               // over float4 groups
        float4 v = ((const float4*)x)[i];
        ushort4 o;
        o.x = f2bf(v.x); o.y = f2bf(v.y); o.z = f2bf(v.z); o.w = f2bf(v.w);
        ((ushort4*)xb)[i] = o;
    } else {
        int row  = (b - 8192) * 4 + (threadIdx.x >> 6);
        int lane = threadIdx.x & 63;
        float4 v = ((const float4*)(cb + (size_t)row * DIM))[lane];
        ushort4 o;
        o.x = f2bf(v.x); o.y = f2bf(v.y); o.z = f2bf(v.z); o.w = f2bf(v.w);
        ((ushort4*)(cbb + (size_t)row * DIM))[lane] = o;
        float s = v.x * v.x + v.y * v.y + v.z * v.z + v.w * v.w;
        #pragma unroll
        for (int off = 32; off > 0; off >>= 1) s += __shfl_down(s, off, 64);
        // +4.0 bias: makes every score positive => float bits are u32-sortable
        if (lane == 0) cbn[row] = s + 4.0f;
    }
}

// ---------------- MFMA GEMM + fused running argmin (N-persistent) ----------------
// Each block: 128 rows x 1024 cols (8 chunks of 128), K=256.
// Running min per (i,r) kept as packed u32: (score_bits & ~0x7F) | local_col,
// plus byte-packed chunk id. Epilogue (shuffle/LDS reduce) once per block.
__global__ __launch_bounds__(256) void vq_argmin_mfma(
        const unsigned short* __restrict__ xb,
        const unsigned short* __restrict__ cbb,
        const float* __restrict__ cbn,     // ||e||^2 + 4.0f
        unsigned long long* __restrict__ partial) {
    __shared__ __align__(16) unsigned short As[128 * 64];
    __shared__ __align__(16) unsigned short Bs[128 * 64];
    __shared__ unsigned long long redk[2][128];

    const int tid = threadIdx.x;
    const int lane = tid & 63;
    const int w = tid >> 6;           // wave 0..3
    const int wm = w >> 1, wn = w & 1;
    const int l15 = lane & 15, q = lane >> 4;
    const int ns = blockIdx.x & 7;    // N-split 0..7
    const int by = blockIdx.x >> 3;   // M tile 0..255
    const int m0 = by * 128;
    const int nbase = ns * 1024;

    const int sub = lane >> 3;        // row-within-segment 0..7
    const int sl  = lane & 7;         // 16B slot 0..7

    unsigned int colb[4];
    #pragma unroll
    for (int j = 0; j < 4; j++) colb[j] = (unsigned)(wn * 64 + j * 16 + l15);

    unsigned int runk[4][4];          // packed (masked score | local col)
    unsigned int runcP[4];            // 4 chunk-id bytes per i (one per r)
    #pragma unroll
    for (int i = 0; i < 4; i++) {
        runcP[i] = 0u;
        #pragma unroll
        for (int r = 0; r < 4; r++) runk[i][r] = 0xFFFFFFFFu;
    }

    for (int ch = 0; ch < 8; ch++) {
        const int n0c = nbase + ch * 128;
        float bnj[4];
        #pragma unroll
        for (int j = 0; j < 4; j++) bnj[j] = cbn[n0c + (int)colb[j]];

        f32x4 acc[4][4];
        #pragma unroll
        for (int i = 0; i < 4; i++)
            #pragma unroll
            for (int j = 0; j < 4; j++) acc[i][j] = (f32x4)0.f;

        for (int kc = 0; kc < 4; kc++) {
            __syncthreads();          // prev compute done before LDS overwrite
            #pragma unroll
            for (int t = 0; t < 4; t++) {
                int seg = t * 4 + w;                   // wave-uniform
                int row = seg * 8 + sub;
                int blk = sl ^ (row & 7);              // XOR swizzle
                const char* gA = (const char*)xb + (size_t)(m0 + row) * 512 + kc * 128 + blk * 16;
                const char* gB = (const char*)cbb + (size_t)(n0c + row) * 512 + kc * 128 + blk * 16;
                GL2LDS(gA, (char*)As + seg * 1024);
                GL2LDS(gB, (char*)Bs + seg * 1024);
            }
            __syncthreads();          // vmcnt(0) drain

            #pragma unroll
            for (int ks = 0; ks < 2; ks++) {
                s8v a[4], b[4];
                #pragma unroll
                for (int i = 0; i < 4; i++) {
                    int row = wm * 64 + i * 16 + l15;
                    int P = (ks * 4 + q) ^ (row & 7);
                    a[i] = *(const s8v*)(As + row * 64 + P * 8);
                }
                #pragma unroll
                for (int j = 0; j < 4; j++) {
                    int row = wn * 64 + j * 16 + l15;
                    int P = (ks * 4 + q) ^ (row & 7);
                    b[j] = *(const s8v*)(Bs + row * 64 + P * 8);
                }
                #pragma unroll
                for (int i = 0; i < 4; i++)
                    #pragma unroll
                    for (int j = 0; j < 4; j++)
                        acc[i][j] = __builtin_amdgcn_mfma_f32_16x16x32_bf16(
                            a[i], b[j], acc[i][j], 0, 0, 0);
            }
        }

        // running-min update: 3 VALU/score (fma, and_or, min) + 6/quad bookkeeping
        #pragma unroll
        for (int i = 0; i < 4; i++) {
            #pragma unroll
            for (int r = 0; r < 4; r++) {
                unsigned int k0 = (__float_as_uint(fmaf(-2.f, acc[i][0][r], bnj[0])) & 0xFFFFFF80u) | colb[0];
                unsigned int k1 = (__float_as_uint(fmaf(-2.f, acc[i][1][r], bnj[1])) & 0xFFFFFF80u) | colb[1];
                unsigned int k2 = (__float_as_uint(fmaf(-2.f, acc[i][2][r], bnj[2])) & 0xFFFFFF80u) | colb[2];
                unsigned int k3 = (__float_as_uint(fmaf(-2.f, acc[i][3][r], bnj[3])) & 0xFFFFFF80u) | colb[3];
                unsigned int km = min(min(k0, k1), min(k2, k3));   // lower col wins ties
                bool u = km < runk[i][r];                          // strict: earlier chunk wins ties
                unsigned int nb = (runcP[i] & ~(0xFFu << (8 * r))) | ((unsigned)ch << (8 * r));
                runk[i][r] = u ? km : runk[i][r];
                runcP[i]   = u ? nb : runcP[i];
            }
        }
    }

    // epilogue, once per block
    #pragma unroll
    for (int i = 0; i < 4; i++) {
        #pragma unroll
        for (int r = 0; r < 4; r++) {
            unsigned int rk = runk[i][r];
            unsigned int chv = (runcP[i] >> (8 * r)) & 0xFFu;
            unsigned int gcol = (unsigned)nbase + chv * 128u + (rk & 127u);
            unsigned long long key =
                ((unsigned long long)(rk & 0xFFFFFF80u) << 32) | gcol;
            #pragma unroll
            for (int off = 8; off >= 1; off >>= 1) {
                unsigned long long o = __shfl_xor(key, off, 16);
                if (o < key) key = o;
            }
            if (l15 == 0) redk[wn][wm * 64 + i * 16 + q * 4 + r] = key;
        }
    }
    __syncthreads();
    if (tid < 128) {
        unsigned long long k0 = redk[0][tid], k1 = redk[1][tid];
        partial[(size_t)(m0 + tid) * 8 + ns] = k0 < k1 ? k0 : k1;
    }
}

// ---------------- reduce 8 partials per row -> index ----------------
__global__ __launch_bounds__(256) void vq_reduce(
        const unsigned long long* __restrict__ partial, int* __restrict__ idx) {
    int row = blockIdx.x * 256 + threadIdx.x;
    const unsigned long long* p = partial + (size_t)row * 8;
    unsigned long long best = p[0];
    #pragma unroll
    for (int t = 1; t < 8; t++) {
        unsigned long long v = p[t];
        if (v < best) best = v;
    }
    idx[row] = (int)(unsigned int)(best & 0xffffffffu);
}

// ---------------- gather + straight-through output + loss partials + counts ----------------
__global__ __launch_bounds__(256) void vq_out(const float* __restrict__ x,
                                              const float* __restrict__ cb,
                                              const int* __restrict__ idx,
                                              float* __restrict__ out,
                                              unsigned int* __restrict__ counts,
                                              double* __restrict__ loss_part) {
    __shared__ float wred[4];
    int wv   = threadIdx.x >> 6;
    int row  = blockIdx.x * 4 + wv;
    int lane = threadIdx.x & 63;
    int id = idx[row];
    float4 qv = ((const float4*)(cb + (size_t)id * DIM))[lane];
    float4 xv = ((const float4*)(x + (size_t)row * DIM))[lane];
    float dx = qv.x - xv.x, dy = qv.y - xv.y, dz = qv.z - xv.z, dw = qv.w - xv.w;
    float4 o;
    o.x = xv.x + dx; o.y = xv.y + dy; o.z = xv.z + dz; o.w = xv.w + dw;
    ((float4*)(out + (size_t)row * DIM))[lane] = o;
    float s = dx * dx + dy * dy + dz * dz + dw * dw;
    #pragma unroll
    for (int o2 = 32; o2 > 0; o2 >>= 1) s += __shfl_down(s, o2, 64);
    if (lane == 0) {
        wred[wv] = s;
        atomicAdd(&counts[id], 1u);
    }
    __syncthreads();
    if (threadIdx.x == 0) {
        loss_part[blockIdx.x] =
            (double)wred[0] + (double)wred[1] + (double)wred[2] + (double)wred[3];
    }
}

// ---------------- finalize loss + perplexity ----------------
__global__ __launch_bounds__(256) void vq_fin(const unsigned int* __restrict__ counts,
                                              const double* __restrict__ loss_part,
                                              float* __restrict__ out_tail) {
    __shared__ double sh[256];
    __shared__ double sl[256];
    int tid = threadIdx.x;
    double h = 0.0;
    for (int k = tid; k < NUM_EMB; k += 256) {
        float p = (float)counts[k] / 32768.0f;
        h += (double)p * log((double)p + 1e-10);
    }
    double ls = 0.0;
    for (int b = tid; b < NROWS / 4; b += 256) ls += loss_part[b];
    sh[tid] = h;
    sl[tid] = ls;
    __syncthreads();
    for (int o = 128; o > 0; o >>= 1) {
        if (tid < o) { sh[tid] += sh[tid + o]; sl[tid] += sl[tid + o]; }
        __syncthreads();
    }
    if (tid == 0) {
        double mean = sl[0] / (double)((size_t)NROWS * DIM);
        out_tail[0] = (float)(1.25 * mean);
        out_tail[1] = (float)exp(-sh[0]);
    }
}

extern "C" void kernel_launch(void* const* d_in, const int* in_sizes, int n_in,
                              void* d_out, int out_size, void* d_ws, size_t ws_size,
                              hipStream_t stream) {
    const float* x  = (const float*)d_in[0];
    const float* cb = (const float*)d_in[1];
    char* ws = (char*)d_ws;
    unsigned int* counts   = (unsigned int*)(ws + 256);          // 32768 B
    int* idx               = (int*)(ws + 33024);                 // 131072 B
    float* cbn             = (float*)(ws + 164096);              // 32768 B
    unsigned short* xb     = (unsigned short*)(ws + 196864);     // 16 MB bf16 x
    unsigned short* cbb    = (unsigned short*)(ws + 196864 + 16777216);   // 4 MB
    unsigned long long* pp = (unsigned long long*)(ws + 196864 + 16777216 + 4194304); // 2 MB used
    double* loss_part      = (double*)(ws + 196864 + 16777216 + 4194304 + 16777216); // 64 KB
    float* out = (float*)d_out;

    (void)hipMemsetAsync(ws, 0, 33024, stream);   // zero counts
    vq_prep       <<<10240, 256, 0, stream>>>(x, xb, cb, cbb, cbn);
    vq_argmin_mfma<<<2048, 256, 0, stream>>>(xb, cbb, cbn, pp);
    vq_reduce     <<<128, 256, 0, stream>>>(pp, idx);
    vq_out        <<<8192, 256, 0, stream>>>(x, cb, idx, out, counts, loss_part);
    vq_fin        <<<1, 256, 0, stream>>>(counts, loss_part, out + (size_t)NROWS * DIM);
}

// Round 6
// 319.363 us; speedup vs baseline: 1.3253x; 1.3253x over previous
//
#include <hip/hip_runtime.h>
#include <cfloat>
#include <math.h>

#define NUM_EMB 8192
#define DIM 256
#define NROWS 32768

typedef short s8v __attribute__((ext_vector_type(8)));   // 8 bf16 in 4 VGPRs
typedef float f32x4 __attribute__((ext_vector_type(4)));

#define GL2LDS(g, l) __builtin_amdgcn_global_load_lds( \
    (const __attribute__((address_space(1))) void*)(g), \
    (__attribute__((address_space(3))) void*)(l), 16, 0, 0)

// fp32 -> bf16 (round-to-nearest-even), header-version-independent
__device__ __forceinline__ unsigned short f2bf(float f) {
    unsigned int u = __float_as_uint(f);
    u += 0x7fffu + ((u >> 16) & 1u);
    return (unsigned short)(u >> 16);
}

// ---------------- fused: x->bf16  +  codebook norms/bf16 ----------------
// blocks [0,8192): convert x ; blocks [8192,10240): codebook rows (4/block)
__global__ __launch_bounds__(256) void vq_prep(const float* __restrict__ x,
                                               unsigned short* __restrict__ xb,
                                               const float* __restrict__ cb,
                                               unsigned short* __restrict__ cbb,
                                               float* __restrict__ cbn) {
    int b = blockIdx.x;
    if (b < 8192) {
        int i = b * 256 + threadIdx.x;               // over float4 groups
        float4 v = ((const float4*)x)[i];
        ushort4 o;
        o.x = f2bf(v.x); o.y = f2bf(v.y); o.z = f2bf(v.z); o.w = f2bf(v.w);
        ((ushort4*)xb)[i] = o;
    } else {
        int row  = (b - 8192) * 4 + (threadIdx.x >> 6);
        int lane = threadIdx.x & 63;
        float4 v = ((const float4*)(cb + (size_t)row * DIM))[lane];
        ushort4 o;
        o.x = f2bf(v.x); o.y = f2bf(v.y); o.z = f2bf(v.z); o.w = f2bf(v.w);
        ((ushort4*)(cbb + (size_t)row * DIM))[lane] = o;
        float s = v.x * v.x + v.y * v.y + v.z * v.z + v.w * v.w;
        #pragma unroll
        for (int off = 32; off > 0; off >>= 1) s += __shfl_down(s, off, 64);
        // +4.0 bias: all scores positive => float bits are u32-monotone sortable
        if (lane == 0) cbn[row] = s + 4.0f;
    }
}

// ---------------- MFMA GEMM + fused argmin (one 128x128 tile per block) ----------------
// score[m][n] = (||e_n||^2+4) - 2 x_m.e_n  (positive; bias cancels in argmin).
// Packed u32 key: (score_bits & ~0x7F) | local_col -> v_min_u32 does
// (min score, ties->lowest col). 16-lane shuffle-min in u32.
__global__ __launch_bounds__(256) void vq_argmin_mfma(
        const unsigned short* __restrict__ xb,
        const unsigned short* __restrict__ cbb,
        const float* __restrict__ cbn,     // ||e||^2 + 4.0f
        unsigned long long* __restrict__ partial) {
    __shared__ __align__(16) unsigned short As[128 * 64];  // [row][k] bf16, swizzled
    __shared__ __align__(16) unsigned short Bs[128 * 64];
    __shared__ unsigned long long redk[2][128];

    const int tid = threadIdx.x;
    const int lane = tid & 63;
    const int w = tid >> 6;           // wave 0..3
    const int wm = w >> 1, wn = w & 1;
    const int l15 = lane & 15, q = lane >> 4;
    const int bx = blockIdx.x & 63;   // N tile (fastest -> A-tile reuse in L2)
    const int by = blockIdx.x >> 6;   // M tile
    const int m0 = by * 128, n0 = bx * 128;

    unsigned int colb[4];
    float bnj[4];
    #pragma unroll
    for (int j = 0; j < 4; j++) {
        colb[j] = (unsigned)(wn * 64 + j * 16 + l15);
        bnj[j] = cbn[n0 + (int)colb[j]];
    }

    f32x4 acc[4][4];
    #pragma unroll
    for (int i = 0; i < 4; i++)
        #pragma unroll
        for (int j = 0; j < 4; j++) acc[i][j] = (f32x4)0.f;

    const int sub = lane >> 3;        // row-within-segment 0..7
    const int sl  = lane & 7;         // 16B slot 0..7

    for (int kc = 0; kc < 4; kc++) {
        __syncthreads();
        #pragma unroll
        for (int t = 0; t < 4; t++) {
            int seg = t * 4 + w;                       // wave-uniform
            int row = seg * 8 + sub;
            int blk = sl ^ (row & 7);                  // XOR swizzle (conflict-free reads)
            const char* gA = (const char*)xb + (size_t)(m0 + row) * 512 + kc * 128 + blk * 16;
            const char* gB = (const char*)cbb + (size_t)(n0 + row) * 512 + kc * 128 + blk * 16;
            GL2LDS(gA, (char*)As + seg * 1024);
            GL2LDS(gB, (char*)Bs + seg * 1024);
        }
        __syncthreads();   // vmcnt(0) drain

        #pragma unroll
        for (int ks = 0; ks < 2; ks++) {
            s8v a[4], b[4];
            #pragma unroll
            for (int i = 0; i < 4; i++) {
                int row = wm * 64 + i * 16 + l15;
                int P = (ks * 4 + q) ^ (row & 7);
                a[i] = *(const s8v*)(As + row * 64 + P * 8);
            }
            #pragma unroll
            for (int j = 0; j < 4; j++) {
                int row = wn * 64 + j * 16 + l15;
                int P = (ks * 4 + q) ^ (row & 7);
                b[j] = *(const s8v*)(Bs + row * 64 + P * 8);
            }
            #pragma unroll
            for (int i = 0; i < 4; i++)
                #pragma unroll
                for (int j = 0; j < 4; j++)
                    acc[i][j] = __builtin_amdgcn_mfma_f32_16x16x32_bf16(
                        a[i], b[j], acc[i][j], 0, 0, 0);
        }
    }

    // cheap epilogue: 3 VALU/score pack+min, u32 shuffle-min over 16 col-lanes
    #pragma unroll
    for (int i = 0; i < 4; i++) {
        #pragma unroll
        for (int r = 0; r < 4; r++) {
            unsigned int km = 0xFFFFFFFFu;
            #pragma unroll
            for (int j = 0; j < 4; j++) {
                unsigned int k =
                    (__float_as_uint(fmaf(-2.f, acc[i][j][r], bnj[j])) & 0xFFFFFF80u) | colb[j];
                km = min(km, k);
            }
            #pragma unroll
            for (int off = 8; off >= 1; off >>= 1)
                km = min(km, (unsigned int)__shfl_xor((int)km, off, 16));
            if (l15 == 0)
                redk[wn][wm * 64 + i * 16 + q * 4 + r] =
                    ((unsigned long long)(km & 0xFFFFFF80u) << 32) |
                    (unsigned int)(n0 + (km & 127u));
        }
    }
    __syncthreads();
    if (tid < 128) {
        unsigned long long k0 = redk[0][tid], k1 = redk[1][tid];
        // [bx][row] layout: consecutive tid -> consecutive addresses (coalesced)
        partial[(size_t)bx * NROWS + m0 + tid] = k0 < k1 ? k0 : k1;
    }
}

// ---------------- reduce 64 partials per row -> index ----------------
__global__ __launch_bounds__(256) void vq_reduce(
        const unsigned long long* __restrict__ partial, int* __restrict__ idx) {
    int row = blockIdx.x * 256 + threadIdx.x;
    unsigned long long best = 0xFFFFFFFFFFFFFFFFull;
    #pragma unroll 8
    for (int t = 0; t < 64; t++) {
        unsigned long long v = partial[(size_t)t * NROWS + row];
        if (v < best) best = v;
    }
    idx[row] = (int)(unsigned int)(best & 0xffffffffu);
}

// ---------------- gather + straight-through output + loss partials + counts ----------------
__global__ __launch_bounds__(256) void vq_out(const float* __restrict__ x,
                                              const float* __restrict__ cb,
                                              const int* __restrict__ idx,
                                              float* __restrict__ out,
                                              unsigned int* __restrict__ counts,
                                              double* __restrict__ loss_part) {
    __shared__ float wred[4];
    int wv   = threadIdx.x >> 6;
    int row  = blockIdx.x * 4 + wv;
    int lane = threadIdx.x & 63;
    int id = idx[row];
    float4 qv = ((const float4*)(cb + (size_t)id * DIM))[lane];
    float4 xv = ((const float4*)(x + (size_t)row * DIM))[lane];
    float dx = qv.x - xv.x, dy = qv.y - xv.y, dz = qv.z - xv.z, dw = qv.w - xv.w;
    float4 o;
    o.x = xv.x + dx; o.y = xv.y + dy; o.z = xv.z + dz; o.w = xv.w + dw;
    ((float4*)(out + (size_t)row * DIM))[lane] = o;
    float s = dx * dx + dy * dy + dz * dz + dw * dw;
    #pragma unroll
    for (int o2 = 32; o2 > 0; o2 >>= 1) s += __shfl_down(s, o2, 64);
    if (lane == 0) {
        wred[wv] = s;
        atomicAdd(&counts[id], 1u);
    }
    __syncthreads();
    if (threadIdx.x == 0) {
        loss_part[blockIdx.x] =
            (double)wred[0] + (double)wred[1] + (double)wred[2] + (double)wred[3];
    }
}

// ---------------- finalize loss + perplexity ----------------
__global__ __launch_bounds__(256) void vq_fin(const unsigned int* __restrict__ counts,
                                              const double* __restrict__ loss_part,
                                              float* __restrict__ out_tail) {
    __shared__ double sh[256];
    __shared__ double sl[256];
    int tid = threadIdx.x;
    double h = 0.0;
    for (int k = tid; k < NUM_EMB; k += 256) {
        float p = (float)counts[k] / 32768.0f;
        h += (double)p * log((double)p + 1e-10);
    }
    double ls = 0.0;
    for (int b = tid; b < NROWS / 4; b += 256) ls += loss_part[b];
    sh[tid] = h;
    sl[tid] = ls;
    __syncthreads();
    for (int o = 128; o > 0; o >>= 1) {
        if (tid < o) { sh[tid] += sh[tid + o]; sl[tid] += sl[tid + o]; }
        __syncthreads();
    }
    if (tid == 0) {
        double mean = sl[0] / (double)((size_t)NROWS * DIM);
        out_tail[0] = (float)(1.25 * mean);
        out_tail[1] = (float)exp(-sh[0]);
    }
}

extern "C" void kernel_launch(void* const* d_in, const int* in_sizes, int n_in,
                              void* d_out, int out_size, void* d_ws, size_t ws_size,
                              hipStream_t stream) {
    const float* x  = (const float*)d_in[0];
    const float* cb = (const float*)d_in[1];
    char* ws = (char*)d_ws;
    unsigned int* counts   = (unsigned int*)(ws + 256);          // 32768 B
    int* idx               = (int*)(ws + 33024);                 // 131072 B
    float* cbn             = (float*)(ws + 164096);              // 32768 B
    unsigned short* xb     = (unsigned short*)(ws + 196864);     // 16 MB bf16 x
    unsigned short* cbb    = (unsigned short*)(ws + 196864 + 16777216);   // 4 MB
    unsigned long long* pp = (unsigned long long*)(ws + 196864 + 16777216 + 4194304); // 16 MB
    double* loss_part      = (double*)(ws + 196864 + 16777216 + 4194304 + 16777216); // 64 KB
    float* out = (float*)d_out;

    (void)hipMemsetAsync(ws, 0, 33024, stream);   // zero counts
    vq_prep       <<<10240, 256, 0, stream>>>(x, xb, cb, cbb, cbn);
    vq_argmin_mfma<<<16384, 256, 0, stream>>>(xb, cbb, cbn, pp);
    vq_reduce     <<<128, 256, 0, stream>>>(pp, idx);
    vq_out        <<<8192, 256, 0, stream>>>(x, cb, idx, out, counts, loss_part);
    vq_fin        <<<1, 256, 0, stream>>>(counts, loss_part, out + (size_t)NROWS * DIM);
}

// Round 7
// 273.777 us; speedup vs baseline: 1.5460x; 1.1665x over previous
//
#include <hip/hip_runtime.h>
#include <cfloat>
#include <math.h>

#define NUM_EMB 8192
#define DIM 256
#define NROWS 32768

typedef float f32x4 __attribute__((ext_vector_type(4)));
typedef int   i32x4 __attribute__((ext_vector_type(4)));
typedef int   i32x8 __attribute__((ext_vector_type(8)));

#define GL2LDS(g, l) __builtin_amdgcn_global_load_lds( \
    (const __attribute__((address_space(1))) void*)(g), \
    (__attribute__((address_space(3))) void*)(l), 16, 0, 0)

// ---------------- prep: x -> fp8 ; codebook -> fp8(e*8192) + biased norms ----------------
// blocks [0,4096): x (8 floats/thread) ; blocks [4096,6144): codebook rows (4/block)
__global__ __launch_bounds__(256) void vq_prep(const float* __restrict__ x,
                                               unsigned char* __restrict__ xq,
                                               const float* __restrict__ cb,
                                               unsigned char* __restrict__ cbq,
                                               float* __restrict__ cbn) {
    int b = blockIdx.x;
    if (b < 4096) {
        int i = b * 256 + threadIdx.x;               // over 8-float groups
        float4 v0 = ((const float4*)x)[2 * i];
        float4 v1 = ((const float4*)x)[2 * i + 1];
        int p0 = __builtin_amdgcn_cvt_pk_fp8_f32(v0.x, v0.y, 0, false);
        p0     = __builtin_amdgcn_cvt_pk_fp8_f32(v0.z, v0.w, p0, true);
        int p1 = __builtin_amdgcn_cvt_pk_fp8_f32(v1.x, v1.y, 0, false);
        p1     = __builtin_amdgcn_cvt_pk_fp8_f32(v1.z, v1.w, p1, true);
        ((int2*)xq)[i] = make_int2(p0, p1);
    } else {
        int row  = (b - 4096) * 4 + (threadIdx.x >> 6);
        int lane = threadIdx.x & 63;
        float4 v = ((const float4*)(cb + (size_t)row * DIM))[lane];
        // store e*8192 in fp8 (range (-1,1)); scale folds out of the argmin
        int p = __builtin_amdgcn_cvt_pk_fp8_f32(v.x * 8192.f, v.y * 8192.f, 0, false);
        p     = __builtin_amdgcn_cvt_pk_fp8_f32(v.z * 8192.f, v.w * 8192.f, p, true);
        ((int*)cbq)[row * 64 + lane] = p;
        float s = v.x * v.x + v.y * v.y + v.z * v.z + v.w * v.w;
        #pragma unroll
        for (int off = 32; off > 0; off >>= 1) s += __shfl_down(s, off, 64);
        // scaled-units norm + 512 bias: scores positive => u32-monotone float bits
        if (lane == 0) cbn[row] = 8192.f * s + 512.f;
    }
}

// ---------------- MX-FP8 MFMA GEMM + fused argmin (128x128 tile per block) ----------------
// score'[m][n] = (8192||e_n||^2+512) - 2*(x_m . 8192 e_n); argmin unchanged.
// Packed u32 key (masked score | local col) -> v_min_u32 keeps lowest col on ties.
__global__ __launch_bounds__(256) void vq_argmin_mfma(
        const unsigned char* __restrict__ xq,
        const unsigned char* __restrict__ cbq,
        const float* __restrict__ cbn,
        unsigned long long* __restrict__ partial) {
    __shared__ __align__(16) unsigned char As[128 * 128];  // [row][128B K-chunk], swizzled
    __shared__ __align__(16) unsigned char Bs[128 * 128];
    __shared__ unsigned long long redk[2][128];

    const int tid = threadIdx.x;
    const int lane = tid & 63;
    const int w = tid >> 6;           // wave 0..3
    const int wm = w >> 1, wn = w & 1;
    const int l15 = lane & 15, q = lane >> 4;
    const int bx = blockIdx.x & 63;   // N tile (fastest -> A-tile L2 reuse)
    const int by = blockIdx.x >> 6;   // M tile
    const int m0 = by * 128, n0 = bx * 128;

    unsigned int colb[4];
    float bnj[4];
    #pragma unroll
    for (int j = 0; j < 4; j++) {
        colb[j] = (unsigned)(wn * 64 + j * 16 + l15);
        bnj[j] = cbn[n0 + (int)colb[j]];
    }

    f32x4 acc[4][4];
    #pragma unroll
    for (int i = 0; i < 4; i++)
        #pragma unroll
        for (int j = 0; j < 4; j++) acc[i][j] = (f32x4)0.f;

    const int sub = lane >> 3;        // row within 8-row segment
    const int sl  = lane & 7;         // 16B slot within 128B chunk-row

    for (int kc = 0; kc < 2; kc++) {  // two 128B K-chunks
        __syncthreads();
        #pragma unroll
        for (int t = 0; t < 4; t++) {
            int seg = t * 4 + w;                       // wave-uniform
            int row = seg * 8 + sub;
            int blk = sl ^ (row & 7);                  // XOR swizzle (bank-balanced reads)
            const char* gA = (const char*)xq + (size_t)(m0 + row) * 256 + kc * 128 + blk * 16;
            const char* gB = (const char*)cbq + (size_t)(n0 + row) * 256 + kc * 128 + blk * 16;
            GL2LDS(gA, (char*)As + seg * 1024);
            GL2LDS(gB, (char*)Bs + seg * 1024);
        }
        __syncthreads();   // vmcnt(0) drain

        i32x8 bfr[4];
        #pragma unroll
        for (int j = 0; j < 4; j++) {
            int row = wn * 64 + j * 16 + l15;
            int s0 = ((2 * q) ^ (row & 7)) * 16;
            int s1 = ((2 * q + 1) ^ (row & 7)) * 16;
            i32x4 lo = *(const i32x4*)(Bs + row * 128 + s0);
            i32x4 hi = *(const i32x4*)(Bs + row * 128 + s1);
            bfr[j] = __builtin_shufflevector(lo, hi, 0, 1, 2, 3, 4, 5, 6, 7);
        }
        #pragma unroll
        for (int i = 0; i < 4; i++) {
            int row = wm * 64 + i * 16 + l15;
            int s0 = ((2 * q) ^ (row & 7)) * 16;
            int s1 = ((2 * q + 1) ^ (row & 7)) * 16;
            i32x4 lo = *(const i32x4*)(As + row * 128 + s0);
            i32x4 hi = *(const i32x4*)(As + row * 128 + s1);
            i32x8 afr = __builtin_shufflevector(lo, hi, 0, 1, 2, 3, 4, 5, 6, 7);
            #pragma unroll
            for (int j = 0; j < 4; j++)
                acc[i][j] = __builtin_amdgcn_mfma_scale_f32_16x16x128_f8f6f4(
                    afr, bfr[j], acc[i][j], 0, 0,    // cbsz=fp8, blgp=fp8
                    0, 127, 0, 127);                 // scales = 2^0
        }
    }

    // cheap epilogue: pack (score|col) u32, v_min chain, 16-lane shuffle-min
    #pragma unroll
    for (int i = 0; i < 4; i++) {
        #pragma unroll
        for (int r = 0; r < 4; r++) {
            unsigned int km = 0xFFFFFFFFu;
            #pragma unroll
            for (int j = 0; j < 4; j++) {
                unsigned int k =
                    (__float_as_uint(fmaf(-2.f, acc[i][j][r], bnj[j])) & 0xFFFFFF80u) | colb[j];
                km = min(km, k);
            }
            #pragma unroll
            for (int off = 8; off >= 1; off >>= 1)
                km = min(km, (unsigned int)__shfl_xor((int)km, off, 16));
            if (l15 == 0)
                redk[wn][wm * 64 + i * 16 + q * 4 + r] =
                    ((unsigned long long)(km & 0xFFFFFF80u) << 32) |
                    (unsigned int)(n0 + (km & 127u));
        }
    }
    __syncthreads();
    if (tid < 128) {
        unsigned long long k0 = redk[0][tid], k1 = redk[1][tid];
        partial[(size_t)bx * NROWS + m0 + tid] = k0 < k1 ? k0 : k1;   // coalesced
    }
}

// ---------------- fused: reduce partials -> gather + outputs + loss + counts ----------------
__global__ __launch_bounds__(256) void vq_out(const float* __restrict__ x,
                                              const float* __restrict__ cb,
                                              const unsigned long long* __restrict__ partial,
                                              float* __restrict__ out,
                                              unsigned int* __restrict__ counts,
                                              double* __restrict__ loss_part) {
    __shared__ float wred[4];
    int wv   = threadIdx.x >> 6;
    int row  = blockIdx.x * 4 + wv;
    int lane = threadIdx.x & 63;
    // 64-lane butterfly min over this row's 64 partials
    unsigned long long k = partial[(size_t)lane * NROWS + row];
    #pragma unroll
    for (int off = 32; off >= 1; off >>= 1) {
        unsigned long long o = __shfl_xor(k, off, 64);
        if (o < k) k = o;
    }
    int id = (int)(unsigned int)(k & 0xffffffffu);   // wave-uniform
    float4 qv = ((const float4*)(cb + (size_t)id * DIM))[lane];
    float4 xv = ((const float4*)(x + (size_t)row * DIM))[lane];
    float dx = qv.x - xv.x, dy = qv.y - xv.y, dz = qv.z - xv.z, dw = qv.w - xv.w;
    float4 o;
    o.x = xv.x + dx; o.y = xv.y + dy; o.z = xv.z + dz; o.w = xv.w + dw;
    ((float4*)(out + (size_t)row * DIM))[lane] = o;
    float s = dx * dx + dy * dy + dz * dz + dw * dw;
    #pragma unroll
    for (int o2 = 32; o2 > 0; o2 >>= 1) s += __shfl_down(s, o2, 64);
    if (lane == 0) {
        wred[wv] = s;
        atomicAdd(&counts[id], 1u);
    }
    __syncthreads();
    if (threadIdx.x == 0) {
        loss_part[blockIdx.x] =
            (double)wred[0] + (double)wred[1] + (double)wred[2] + (double)wred[3];
    }
}

// ---------------- finalize loss + perplexity ----------------
__global__ __launch_bounds__(256) void vq_fin(const unsigned int* __restrict__ counts,
                                              const double* __restrict__ loss_part,
                                              float* __restrict__ out_tail) {
    __shared__ double sh[256];
    __shared__ double sl[256];
    int tid = threadIdx.x;
    double h = 0.0;
    for (int k = tid; k < NUM_EMB; k += 256) {
        float p = (float)counts[k] / 32768.0f;
        h += (double)p * log((double)p + 1e-10);
    }
    double ls = 0.0;
    for (int b = tid; b < NROWS / 4; b += 256) ls += loss_part[b];
    sh[tid] = h;
    sl[tid] = ls;
    __syncthreads();
    for (int o = 128; o > 0; o >>= 1) {
        if (tid < o) { sh[tid] += sh[tid + o]; sl[tid] += sl[tid + o]; }
        __syncthreads();
    }
    if (tid == 0) {
        double mean = sl[0] / (double)((size_t)NROWS * DIM);
        out_tail[0] = (float)(1.25 * mean);
        out_tail[1] = (float)exp(-sh[0]);
    }
}

extern "C" void kernel_launch(void* const* d_in, const int* in_sizes, int n_in,
                              void* d_out, int out_size, void* d_ws, size_t ws_size,
                              hipStream_t stream) {
    const float* x  = (const float*)d_in[0];
    const float* cb = (const float*)d_in[1];
    char* ws = (char*)d_ws;
    unsigned int* counts   = (unsigned int*)(ws + 256);                 // 32 KB
    float* cbn             = (float*)(ws + 33024);                      // 32 KB
    unsigned char* xq      = (unsigned char*)(ws + 65792);              // 8 MB fp8 x
    unsigned char* cbq     = (unsigned char*)(ws + 65792 + 8388608);    // 2 MB fp8 e*8192
    unsigned long long* pp = (unsigned long long*)(ws + 65792 + 8388608 + 2097152); // 16 MB
    double* loss_part      = (double*)(ws + 65792 + 8388608 + 2097152 + 16777216);  // 64 KB
    float* out = (float*)d_out;

    (void)hipMemsetAsync(ws, 0, 33024, stream);   // zero counts
    vq_prep       <<<6144, 256, 0, stream>>>(x, xq, cb, cbq, cbn);
    vq_argmin_mfma<<<16384, 256, 0, stream>>>(xq, cbq, cbn, pp);
    vq_out        <<<8192, 256, 0, stream>>>(x, cb, pp, out, counts, loss_part);
    vq_fin        <<<1, 256, 0, stream>>>(counts, loss_part, out + (size_t)NROWS * DIM);
}

// Round 8
// 216.513 us; speedup vs baseline: 1.9549x; 1.2645x over previous
//
#include <hip/hip_runtime.h>
#include <cfloat>
#include <math.h>

#define NUM_EMB 8192
#define DIM 256
#define NROWS 32768
#define NSPLIT 4
#define CHUNKS 16   // 8192 / NSPLIT / 128

typedef float f32x4 __attribute__((ext_vector_type(4)));
typedef int   i32x4 __attribute__((ext_vector_type(4)));
typedef int   i32x8 __attribute__((ext_vector_type(8)));

#define GL2LDS(g, l) __builtin_amdgcn_global_load_lds( \
    (const __attribute__((address_space(1))) void*)(g), \
    (__attribute__((address_space(3))) void*)(l), 16, 0, 0)

// ---------------- prep: x -> fp8 ; codebook -> fp8(e*8192) + biased norms ; zero counts ----------------
__global__ __launch_bounds__(256) void vq_prep(const float* __restrict__ x,
                                               unsigned char* __restrict__ xq,
                                               const float* __restrict__ cb,
                                               unsigned char* __restrict__ cbq,
                                               float* __restrict__ cbn,
                                               unsigned int* __restrict__ counts) {
    int b = blockIdx.x;
    if (b < 4096) {
        int i = b * 256 + threadIdx.x;               // over 8-float groups
        float4 v0 = ((const float4*)x)[2 * i];
        float4 v1 = ((const float4*)x)[2 * i + 1];
        int p0 = __builtin_amdgcn_cvt_pk_fp8_f32(v0.x, v0.y, 0, false);
        p0     = __builtin_amdgcn_cvt_pk_fp8_f32(v0.z, v0.w, p0, true);
        int p1 = __builtin_amdgcn_cvt_pk_fp8_f32(v1.x, v1.y, 0, false);
        p1     = __builtin_amdgcn_cvt_pk_fp8_f32(v1.z, v1.w, p1, true);
        ((int2*)xq)[i] = make_int2(p0, p1);
    } else if (b < 6144) {
        int row  = (b - 4096) * 4 + (threadIdx.x >> 6);
        int lane = threadIdx.x & 63;
        float4 v = ((const float4*)(cb + (size_t)row * DIM))[lane];
        // store e*8192 in fp8 (range (-1,1)); scale folds out of the argmin
        int p = __builtin_amdgcn_cvt_pk_fp8_f32(v.x * 8192.f, v.y * 8192.f, 0, false);
        p     = __builtin_amdgcn_cvt_pk_fp8_f32(v.z * 8192.f, v.w * 8192.f, p, true);
        ((int*)cbq)[row * 64 + lane] = p;
        float s = v.x * v.x + v.y * v.y + v.z * v.z + v.w * v.w;
        #pragma unroll
        for (int off = 32; off > 0; off >>= 1) s += __shfl_down(s, off, 64);
        // scaled-units norm + 512 bias: scores positive => u32-monotone float bits
        if (lane == 0) cbn[row] = 8192.f * s + 512.f;
    } else {
        counts[(b - 6144) * 256 + threadIdx.x] = 0u;
    }
}

// ---------------- MX-FP8 MFMA GEMM + fused running argmin ----------------
// Block: 128 rows x 2048 cols (16 chunks of 128). A-tile resident in LDS.
// score'[m][n] = (8192||e_n||^2+512) - 2*(x_m . 8192 e_n).
// Running u32 key per (i,r): (score_bits & ~0x7F) | local_col; chunk id in
// byte-packed runcP. Strict < keeps earlier chunk (=> lowest index on ties).
__global__ __launch_bounds__(256) void vq_argmin_mfma(
        const unsigned char* __restrict__ xq,
        const unsigned char* __restrict__ cbq,
        const float* __restrict__ cbn,
        unsigned long long* __restrict__ partial) {
    __shared__ __align__(16) unsigned char As[2][128 * 128]; // kc-halves, [row][128B] swizzled
    __shared__ __align__(16) unsigned char Bs[128 * 128];
    __shared__ unsigned long long redk[2][128];

    const int tid = threadIdx.x;
    const int lane = tid & 63;
    const int w = tid >> 6;           // wave 0..3
    const int wm = w >> 1, wn = w & 1;
    const int l15 = lane & 15, q = lane >> 4;
    const int ns = blockIdx.x & (NSPLIT - 1);
    const int by = blockIdx.x / NSPLIT;
    const int m0 = by * 128;
    const int nbase = ns * (NUM_EMB / NSPLIT);

    const int sub = lane >> 3;        // row within 8-row segment
    const int sl  = lane & 7;         // 16B slot within 128B chunk-row

    // stage A once: 128 rows x 256B, two kc halves
    #pragma unroll
    for (int kc = 0; kc < 2; kc++)
        #pragma unroll
        for (int t = 0; t < 4; t++) {
            int seg = t * 4 + w;                   // wave-uniform
            int row = seg * 8 + sub;
            int blk = sl ^ (row & 7);              // XOR swizzle
            GL2LDS((const char*)xq + (size_t)(m0 + row) * 256 + kc * 128 + blk * 16,
                   (char*)As[kc] + seg * 1024);
        }

    unsigned int colb[4];
    #pragma unroll
    for (int j = 0; j < 4; j++) colb[j] = (unsigned)(wn * 64 + j * 16 + l15);

    unsigned int runk[4][4];
    unsigned int runcP[4];
    #pragma unroll
    for (int i = 0; i < 4; i++) {
        runcP[i] = 0u;
        #pragma unroll
        for (int r = 0; r < 4; r++) runk[i][r] = 0xFFFFFFFFu;
    }

    #pragma unroll 1
    for (int ch = 0; ch < CHUNKS; ch++) {
        const int n0c = nbase + ch * 128;
        float bnj[4];
        #pragma unroll
        for (int j = 0; j < 4; j++) bnj[j] = cbn[n0c + (int)colb[j]];

        f32x4 acc[4][4];
        #pragma unroll
        for (int i = 0; i < 4; i++)
            #pragma unroll
            for (int j = 0; j < 4; j++) acc[i][j] = (f32x4)0.f;

        #pragma unroll
        for (int kc = 0; kc < 2; kc++) {
            __syncthreads();          // prev compute done before Bs overwrite
            #pragma unroll
            for (int t = 0; t < 4; t++) {
                int seg = t * 4 + w;
                int row = seg * 8 + sub;
                int blk = sl ^ (row & 7);
                GL2LDS((const char*)cbq + (size_t)(n0c + row) * 256 + kc * 128 + blk * 16,
                       (char*)Bs + seg * 1024);
            }
            __syncthreads();          // vmcnt(0) drain (covers A on first iter)

            i32x8 bfr[4];
            #pragma unroll
            for (int j = 0; j < 4; j++) {
                int row = wn * 64 + j * 16 + l15;
                int s0 = ((2 * q) ^ (row & 7)) * 16;
                int s1 = ((2 * q + 1) ^ (row & 7)) * 16;
                i32x4 lo = *(const i32x4*)(Bs + row * 128 + s0);
                i32x4 hi = *(const i32x4*)(Bs + row * 128 + s1);
                bfr[j] = __builtin_shufflevector(lo, hi, 0, 1, 2, 3, 4, 5, 6, 7);
            }
            #pragma unroll
            for (int i = 0; i < 4; i++) {
                int row = wm * 64 + i * 16 + l15;
                int s0 = ((2 * q) ^ (row & 7)) * 16;
                int s1 = ((2 * q + 1) ^ (row & 7)) * 16;
                i32x4 lo = *(const i32x4*)(As[kc] + row * 128 + s0);
                i32x4 hi = *(const i32x4*)(As[kc] + row * 128 + s1);
                i32x8 afr = __builtin_shufflevector(lo, hi, 0, 1, 2, 3, 4, 5, 6, 7);
                #pragma unroll
                for (int j = 0; j < 4; j++)
                    acc[i][j] = __builtin_amdgcn_mfma_scale_f32_16x16x128_f8f6f4(
                        afr, bfr[j], acc[i][j], 0, 0,    // fp8 / fp8
                        0, 127, 0, 127);                 // scales = 2^0
            }
        }

        // running-min update: fmaf + and_or pack, 3 min, select
        #pragma unroll
        for (int i = 0; i < 4; i++) {
            #pragma unroll
            for (int r = 0; r < 4; r++) {
                unsigned int k0 = (__float_as_uint(fmaf(-2.f, acc[i][0][r], bnj[0])) & 0xFFFFFF80u) | colb[0];
                unsigned int k1 = (__float_as_uint(fmaf(-2.f, acc[i][1][r], bnj[1])) & 0xFFFFFF80u) | colb[1];
                unsigned int k2 = (__float_as_uint(fmaf(-2.f, acc[i][2][r], bnj[2])) & 0xFFFFFF80u) | colb[2];
                unsigned int k3 = (__float_as_uint(fmaf(-2.f, acc[i][3][r], bnj[3])) & 0xFFFFFF80u) | colb[3];
                unsigned int km = min(min(k0, k1), min(k2, k3));
                bool u = km < runk[i][r];
                unsigned int nb = (runcP[i] & ~(0xFFu << (8 * r))) | ((unsigned)ch << (8 * r));
                runk[i][r] = u ? km : runk[i][r];
                runcP[i]   = u ? nb : runcP[i];
            }
        }
    }

    // epilogue once per block: full u64 (score, global col) shuffle-min
    #pragma unroll
    for (int i = 0; i < 4; i++) {
        #pragma unroll
        for (int r = 0; r < 4; r++) {
            unsigned int rk = runk[i][r];
            unsigned int chv = (runcP[i] >> (8 * r)) & 0xFFu;
            unsigned int gcol = (unsigned)nbase + chv * 128u + (rk & 127u);
            unsigned long long key =
                ((unsigned long long)(rk & 0xFFFFFF80u) << 32) | gcol;
            #pragma unroll
            for (int off = 8; off >= 1; off >>= 1) {
                unsigned long long o = __shfl_xor(key, off, 16);
                if (o < key) key = o;
            }
            if (l15 == 0) redk[wn][wm * 64 + i * 16 + q * 4 + r] = key;
        }
    }
    __syncthreads();
    if (tid < 128) {
        unsigned long long k0 = redk[0][tid], k1 = redk[1][tid];
        partial[(size_t)ns * NROWS + m0 + tid] = k0 < k1 ? k0 : k1;   // coalesced
    }
}

// ---------------- fused: reduce partials -> gather + outputs + loss + counts ----------------
__global__ __launch_bounds__(256) void vq_out(const float* __restrict__ x,
                                              const float* __restrict__ cb,
                                              const unsigned long long* __restrict__ partial,
                                              float* __restrict__ out,
                                              unsigned int* __restrict__ counts,
                                              double* __restrict__ loss_part) {
    __shared__ float wred[4];
    int wv   = threadIdx.x >> 6;
    int row  = blockIdx.x * 4 + wv;
    int lane = threadIdx.x & 63;
    unsigned long long k = 0xFFFFFFFFFFFFFFFFull;
    #pragma unroll
    for (int t = 0; t < NSPLIT; t++) {
        unsigned long long v = partial[(size_t)t * NROWS + row];
        if (v < k) k = v;
    }
    int id = (int)(unsigned int)(k & 0xffffffffu);   // wave-uniform
    float4 qv = ((const float4*)(cb + (size_t)id * DIM))[lane];
    float4 xv = ((const float4*)(x + (size_t)row * DIM))[lane];
    float dx = qv.x - xv.x, dy = qv.y - xv.y, dz = qv.z - xv.z, dw = qv.w - xv.w;
    float4 o;
    o.x = xv.x + dx; o.y = xv.y + dy; o.z = xv.z + dz; o.w = xv.w + dw;
    ((float4*)(out + (size_t)row * DIM))[lane] = o;
    float s = dx * dx + dy * dy + dz * dz + dw * dw;
    #pragma unroll
    for (int o2 = 32; o2 > 0; o2 >>= 1) s += __shfl_down(s, o2, 64);
    if (lane == 0) {
        wred[wv] = s;
        atomicAdd(&counts[id], 1u);
    }
    __syncthreads();
    if (threadIdx.x == 0) {
        loss_part[blockIdx.x] =
            (double)wred[0] + (double)wred[1] + (double)wred[2] + (double)wred[3];
    }
}

// ---------------- finalize loss + perplexity ----------------
__global__ __launch_bounds__(256) void vq_fin(const unsigned int* __restrict__ counts,
                                              const double* __restrict__ loss_part,
                                              float* __restrict__ out_tail) {
    __shared__ double sh[256];
    __shared__ double sl[256];
    int tid = threadIdx.x;
    double h = 0.0;
    for (int k = tid; k < NUM_EMB; k += 256) {
        float p = (float)counts[k] / 32768.0f;
        h += (double)p * log((double)p + 1e-10);
    }
    double ls = 0.0;
    for (int b = tid; b < NROWS / 4; b += 256) ls += loss_part[b];
    sh[tid] = h;
    sl[tid] = ls;
    __syncthreads();
    for (int o = 128; o > 0; o >>= 1) {
        if (tid < o) { sh[tid] += sh[tid + o]; sl[tid] += sl[tid + o]; }
        __syncthreads();
    }
    if (tid == 0) {
        double mean = sl[0] / (double)((size_t)NROWS * DIM);
        out_tail[0] = (float)(1.25 * mean);
        out_tail[1] = (float)exp(-sh[0]);
    }
}

extern "C" void kernel_launch(void* const* d_in, const int* in_sizes, int n_in,
                              void* d_out, int out_size, void* d_ws, size_t ws_size,
                              hipStream_t stream) {
    const float* x  = (const float*)d_in[0];
    const float* cb = (const float*)d_in[1];
    char* ws = (char*)d_ws;
    unsigned int* counts   = (unsigned int*)(ws + 256);                 // 32 KB
    float* cbn             = (float*)(ws + 33024);                      // 32 KB
    unsigned char* xq      = (unsigned char*)(ws + 65792);              // 8 MB fp8 x
    unsigned char* cbq     = (unsigned char*)(ws + 65792 + 8388608);    // 2 MB fp8 e*8192
    unsigned long long* pp = (unsigned long long*)(ws + 65792 + 8388608 + 2097152); // 1 MB
    double* loss_part      = (double*)(ws + 65792 + 8388608 + 2097152 + 16777216);  // 64 KB
    float* out = (float*)d_out;

    vq_prep       <<<6176, 256, 0, stream>>>(x, xq, cb, cbq, cbn, counts);
    vq_argmin_mfma<<<256 * NSPLIT, 256, 0, stream>>>(xq, cbq, cbn, pp);
    vq_out        <<<8192, 256, 0, stream>>>(x, cb, pp, out, counts, loss_part);
    vq_fin        <<<1, 256, 0, stream>>>(counts, loss_part, out + (size_t)NROWS * DIM);
}